// Round 16
// baseline (408.800 us; speedup 1.0000x reference)
//
#include <hip/hip_runtime.h>

typedef __bf16 bf16_t;
typedef __bf16 bf16x8 __attribute__((ext_vector_type(8)));
typedef float  f32x4  __attribute__((ext_vector_type(4)));
typedef _Float16 h16;
typedef _Float16 h16x2 __attribute__((ext_vector_type(2)));
typedef _Float16 h16x4 __attribute__((ext_vector_type(4)));
typedef _Float16 h16x8 __attribute__((ext_vector_type(8)));

#define DEVINL __device__ __forceinline__

static constexpr size_t N_PIX = 16384;
static constexpr float  FIX_TAU = 2.5e-3f;

// ---------------- per-batch workspace layout (bytes) ----------------
static constexpr size_t OFF_QB  = 0;                                   // Qb f16 [512][N] (pre-relu; flagged pixels repaired exact in-place)
static constexpr size_t SZ_QB   = (size_t)512 * N_PIX * 2;
static constexpr size_t OFF_KV  = OFF_QB + SZ_QB;                      // KV f16 [1024][N]
static constexpr size_t SZ_KV   = (size_t)1024 * N_PIX * 2;
static constexpr size_t OFF_Y   = OFF_KV + SZ_KV;                      // y f16 [1536][N]
static constexpr size_t SZ_Y    = (size_t)1536 * N_PIX * 2;
static constexpr size_t OFF_ATT = OFF_Y + SZ_Y;                        // qnT bf16 [N][1024]; xT/xTl f16 aliased
static constexpr size_t SZ_ATT  = (size_t)N_PIX * 1024 * 2;
static constexpr size_t OFF_XT  = OFF_ATT;                             // xT f16 [N][512] (dead after fix; qn overwrites)
static constexpr size_t OFF_XTL = OFF_ATT + (size_t)N_PIX * 512 * 2;   // xT_lo f16 [N][512] (residual)
static constexpr size_t OFF_WALL= OFF_ATT + SZ_ATT;                    // wall f16 [1536][512]: q | k | v (head-major 8-row groups)
static constexpr size_t SZ_WALL = (size_t)1536 * 512 * 2;
static constexpr size_t OFF_WP  = OFF_WALL + SZ_WALL;                  // wpb bf16 [512][1024], pre-scaled by bn inv
static constexpr size_t SZ_WP   = (size_t)512 * 1024 * 2;
static constexpr size_t OFF_VK  = OFF_WP + SZ_WP;                      // vk f32 [128][72]
static constexpr size_t SZ_VK   = (size_t)128 * 72 * 4;
static constexpr size_t OFF_VKP = OFF_VK + SZ_VK;                      // vk partials f32 [128][8][72]
static constexpr size_t SZ_VKP  = (size_t)128 * 8 * 72 * 4;
static constexpr size_t OFF_BNA = OFF_VKP + SZ_VKP;                    // f32[512]
static constexpr size_t OFF_ZP  = OFF_BNA + 2048;                      // 64B zero page
static constexpr size_t OFF_W2  = OFF_ZP + 64;                         // W2 bf16 [512][1024]
static constexpr size_t SZ_W2   = (size_t)512 * 1024 * 2;
static constexpr size_t WS_NEEDED = OFF_W2 + SZ_W2;                    // ~139 MB

// ---------------- helpers ----------------
DEVINL void gload16(const void* g, void* l) {
  __builtin_amdgcn_global_load_lds((const __attribute__((address_space(1))) void*)g,
                                   (__attribute__((address_space(3))) void*)l, 16, 0, 0);
}

// ---------------- K0a: transpose x (f32 [512][N]) -> xT / xT_lo (f16 [N][512]) ----------------
__global__ __launch_bounds__(256)
void xpose_kernel(const float* __restrict__ x, h16* __restrict__ xT, h16* __restrict__ xTl) {
  __shared__ float t[32][33];
  const int n0 = blockIdx.x * 32, c0 = blockIdx.y * 32;
  const int tx = threadIdx.x & 31, ty = threadIdx.x >> 5;
#pragma unroll
  for (int r = 0; r < 4; ++r)
    t[ty + r * 8][tx] = x[(size_t)(c0 + ty + r * 8) * N_PIX + n0 + tx];  // t[c][n]
  __syncthreads();
  const int nl = threadIdx.x >> 3, sub = threadIdx.x & 7;
  const int c8 = (sub & 3) * 8, plane = sub >> 2;
  h16x8 o;
#pragma unroll
  for (int k = 0; k < 8; ++k) {
    const float v = t[c8 + k][nl];
    if (plane == 0) {
      o[k] = (h16)v;
    } else {
      const h16 hi = (h16)v;
      o[k] = (h16)(v - (float)hi);
    }
  }
  h16* dst = plane ? xTl : xT;
  *(h16x8*)&dst[(size_t)(n0 + nl) * 512 + c0 + c8] = o;
}

// ---------------- K0b: build wall f16, scaled wpb, bna, zero page ----------------
static constexpr int PREP_P1 = 1536 * 512;           // wall
static constexpr int PREP_P2 = 512 * 1024;           // wpb
static constexpr int PREP_TOT = PREP_P1 + PREP_P2 + 512 + 16;
__global__ __launch_bounds__(256)
void prep_kernel(const float* __restrict__ wq, const float* __restrict__ wp,
                 const float* __restrict__ gam, const float* __restrict__ bet,
                 const float* __restrict__ mu, const float* __restrict__ va,
                 h16* __restrict__ wall, bf16_t* __restrict__ wpb,
                 float* __restrict__ bna, float* __restrict__ zp) {
  const int i = blockIdx.x * 256 + threadIdx.x;
  if (i < PREP_P1) {
    const int r = i >> 9, c = i & 511;
    int o;
    if (r < 512)       o = (r >> 3) * 24 + (r & 7);               // q
    else if (r < 1024) o = ((r - 512) >> 3) * 24 + 8 + (r & 7);   // k
    else               o = ((r - 1024) >> 3) * 24 + 16 + (r & 7); // v
    wall[i] = (h16)wq[(size_t)o * 512 + c];
  } else if (i < PREP_P1 + PREP_P2) {
    const int j = i - PREP_P1;
    const int m = j >> 10;
    const float inv = gam[m] / sqrtf(va[m] + 1e-5f);
    wpb[j] = (bf16_t)(wp[j] * inv);
  } else if (i < PREP_P1 + PREP_P2 + 512) {
    const int k = i - PREP_P1 - PREP_P2;
    const float inv = gam[k] / sqrtf(va[k] + 1e-5f);
    bna[k] = bet[k] - mu[k] * inv;
  } else if (i < PREP_TOT) {
    zp[i - (PREP_P1 + PREP_P2 + 512)] = 0.f;
  }
}

// ---------------- K1: unified qkv GEMM, f16 MFMA, 128x256 tile, BK=64, swizzled LDS ----------------
__global__ __launch_bounds__(256, 3)
void gemm_qkv_kernel(const h16* __restrict__ wall, const h16* __restrict__ xT,
                     h16* __restrict__ Qb, h16* __restrict__ KV) {
  __shared__ __align__(16) h16 As[128 * 64];   // 16 KB
  __shared__ __align__(16) h16 Bs[256 * 64];   // 32 KB
  const int tid = threadIdx.x, wid = tid >> 6, lane = tid & 63;
  const int fr = lane & 15, fg = lane >> 4;
  const int wm = (wid >> 1) * 64, wn = (wid & 1) * 128;
  const int by = blockIdx.y;
  const bool isQ = by < 4;
  const int m0 = (isQ ? by : by - 4) * 128;
  const int n0 = blockIdx.x * 256;
  const h16* Aptr = wall + (size_t)by * 128 * 512;

  f32x4 acc[4][8] = {};

  for (int kk = 0; kk < 512; kk += 64) {
    __syncthreads();  // prev iter's LDS reads done
#pragma unroll
    for (int r = 0; r < 4; ++r) {
      const int c = wid * 64 + lane + 256 * r;
      const int row = c >> 3, cc = c & 7;
      gload16(Aptr + (size_t)row * 512 + kk + ((cc ^ (row & 7)) * 8),
              As + (size_t)(wid * 64 + 256 * r) * 8);
    }
#pragma unroll
    for (int r = 0; r < 8; ++r) {
      const int c = wid * 64 + lane + 256 * r;
      const int row = c >> 3, cc = c & 7;
      gload16(xT + (size_t)(n0 + row) * 512 + kk + ((cc ^ (row & 7)) * 8),
              Bs + (size_t)(wid * 64 + 256 * r) * 8);
    }
    __syncthreads();  // drains vmcnt(0)
#pragma unroll
    for (int ks = 0; ks < 2; ++ks) {
      h16x8 af[4], bfr[8];
#pragma unroll
      for (int i = 0; i < 4; ++i)
        af[i]  = *(const h16x8*)&As[(wm + i * 16 + fr) * 64 + (((ks * 4 + fg) ^ (fr & 7)) * 8)];
#pragma unroll
      for (int j = 0; j < 8; ++j)
        bfr[j] = *(const h16x8*)&Bs[(wn + j * 16 + fr) * 64 + (((ks * 4 + fg) ^ (fr & 7)) * 8)];
#pragma unroll
      for (int i = 0; i < 4; ++i)
#pragma unroll
        for (int j = 0; j < 8; ++j)
          acc[i][j] = __builtin_amdgcn_mfma_f32_16x16x32_f16(af[i], bfr[j], acc[i][j], 0, 0, 0);
    }
  }

#pragma unroll
  for (int i = 0; i < 4; ++i)
#pragma unroll
    for (int r = 0; r < 4; ++r) {
      const int m = m0 + wm + i * 16 + fg * 4 + r;
      h16* dst = isQ ? Qb : KV;
#pragma unroll
      for (int j = 0; j < 8; ++j) {
        const int n = n0 + wn + j * 16 + fr;
        dst[(size_t)m * N_PIX + n] = (h16)acc[i][j][r];
      }
    }
}

// ---------------- K1b: knife-edge detect + wave-parallel exact IN-PLACE repair of Qb ----------------
__global__ __launch_bounds__(256)
void fix_kernel(const float* __restrict__ wq, const h16* __restrict__ xT,
                const h16* __restrict__ xTl, h16* __restrict__ Qb) {
  const int h = blockIdx.y;
  const int n = blockIdx.x * 256 + threadIdx.x;
  const int lane = threadIdx.x & 63;
  float mx = 0.f;
#pragma unroll
  for (int e = 0; e < 8; ++e)
    mx = fmaxf(mx, (float)Qb[(size_t)(h * 8 + e) * N_PIX + n]);
  unsigned long long mask = __ballot(mx < FIX_TAU);  // wave-uniform
  const int cb = blockIdx.x * 256 + ((int)threadIdx.x & ~63);  // wave's chunk base
  while (mask) {
    const int bit = __builtin_ctzll(mask);
    mask &= mask - 1;
    const int np = cb + bit;
    const int c0 = lane * 8;
    const h16x8 xh = *(const h16x8*)&xT[(size_t)np * 512 + c0];
    const h16x8 xl = *(const h16x8*)&xTl[(size_t)np * 512 + c0];
    float xs[8];
#pragma unroll
    for (int u = 0; u < 8; ++u) xs[u] = (float)xh[u] + (float)xl[u];
    float acc[8];
#pragma unroll
    for (int e = 0; e < 8; ++e) {
      const float4 w0 = *(const float4*)&wq[(size_t)(h * 24 + e) * 512 + c0];
      const float4 w1 = *(const float4*)&wq[(size_t)(h * 24 + e) * 512 + c0 + 4];
      acc[e] = w0.x * xs[0] + w0.y * xs[1] + w0.z * xs[2] + w0.w * xs[3]
             + w1.x * xs[4] + w1.y * xs[5] + w1.z * xs[6] + w1.w * xs[7];
    }
#pragma unroll
    for (int e = 0; e < 8; ++e) {
      acc[e] += __shfl_xor(acc[e], 32); acc[e] += __shfl_xor(acc[e], 16);
      acc[e] += __shfl_xor(acc[e], 8);  acc[e] += __shfl_xor(acc[e], 4);
      acc[e] += __shfl_xor(acc[e], 2);  acc[e] += __shfl_xor(acc[e], 1);
    }
    if (lane < 8) {
      float v = acc[0];
#pragma unroll
      for (int e = 1; e < 8; ++e) if (lane == e) v = acc[e];  // compile-time indices
      Qb[(size_t)(h * 8 + lane) * N_PIX + np] = (h16)v;       // exact pre-relu value
    }
  }
}

// ---------------- K5: proj GEMM out = W2 x qnT + bna, 128x128 tile, BK=64, swizzled ----------------
__global__ __launch_bounds__(256, 4)
void gemm_proj_kernel(const bf16_t* __restrict__ A, const bf16_t* __restrict__ B,
                      float* __restrict__ Cout, const float* __restrict__ bna) {
  __shared__ __align__(16) bf16_t As[128 * 64];
  __shared__ __align__(16) bf16_t Bs[128 * 64];
  const int tid = threadIdx.x, wid = tid >> 6, lane = tid & 63;
  const int fr = lane & 15, fg = lane >> 4;
  const int wm = (wid >> 1) * 64, wn = (wid & 1) * 64;
  const int m0 = blockIdx.y * 128, n0 = blockIdx.x * 128;
  const int srow = tid >> 3;
  const int soff = (((tid & 7) ^ (srow & 7)) * 8);
  const bf16_t* Ab = A + (size_t)m0 * 1024;
  const bf16_t* Bb = B + (size_t)n0 * 1024;

  f32x4 acc[4][4] = {};

  for (int kk = 0; kk < 1024; kk += 64) {
    __syncthreads();
#pragma unroll
    for (int r = 0; r < 4; ++r) {
      gload16(Ab + (size_t)(srow + 32 * r) * 1024 + kk + soff, As + (wid * 8 + 32 * r) * 64);
      gload16(Bb + (size_t)(srow + 32 * r) * 1024 + kk + soff, Bs + (wid * 8 + 32 * r) * 64);
    }
    __syncthreads();
#pragma unroll
    for (int ks = 0; ks < 2; ++ks) {
      bf16x8 af[4], bfr[4];
#pragma unroll
      for (int i = 0; i < 4; ++i)
        af[i]  = *(const bf16x8*)&As[(wm + i * 16 + fr) * 64 + (((ks * 4 + fg) ^ (fr & 7)) * 8)];
#pragma unroll
      for (int j = 0; j < 4; ++j)
        bfr[j] = *(const bf16x8*)&Bs[(wn + j * 16 + fr) * 64 + (((ks * 4 + fg) ^ (fr & 7)) * 8)];
#pragma unroll
      for (int i = 0; i < 4; ++i)
#pragma unroll
        for (int j = 0; j < 4; ++j)
          acc[i][j] = __builtin_amdgcn_mfma_f32_16x16x32_bf16(af[i], bfr[j], acc[i][j], 0, 0, 0);
    }
  }

#pragma unroll
  for (int i = 0; i < 4; ++i)
#pragma unroll
    for (int r = 0; r < 4; ++r) {
      const int m = m0 + wm + i * 16 + fg * 4 + r;
      const float sh = bna[m];
#pragma unroll
      for (int j = 0; j < 4; ++j)
        Cout[(size_t)m * N_PIX + n0 + wn + j * 16 + fr] = acc[i][j][r] + sh;
    }
}

// ---------------- K2: fused dw 5x5 + grouped 1x1; channel-split async pipeline, XCD-remapped ----------------
__global__ __launch_bounds__(256)
void dwpw_kernel(const h16* __restrict__ Qb, const h16* __restrict__ KV,
                 const float* __restrict__ wdw, const float* __restrict__ wpw,
                 const h16* __restrict__ zp, h16* __restrict__ y) {
  const int bidHW = blockIdx.x + (blockIdx.y << 4);          // gridDim = (16,192)
  const int work  = (bidHW & 7) * 384 + (bidHW >> 3);
  const int g = work >> 4, t = work & 15;
  const int typ = g % 3, head = g / 3;
  const int ty0 = (t >> 1) * 16, tx0 = (t & 1) * 64;
  const int tid = threadIdx.x, wid = tid >> 6, lane = tid & 63;
  __shared__ __align__(16) h16 sin_[8][20][80];
  __shared__ h16x2 swd2[8][25];
  __shared__ h16x2 swp2[8][8];
  if (tid < 200) {
    const h16 w = (h16)wdw[(g * 8 + tid / 25) * 25 + tid % 25];
    h16x2 w2; w2[0] = w; w2[1] = w;
    swd2[tid / 25][tid % 25] = w2;
  }
  if (tid < 64) {
    const h16 w = (h16)wpw[(g * 8 + (tid >> 3)) * 8 + (tid & 7)];
    h16x2 w2; w2[0] = w; w2[1] = w;
    swp2[tid >> 3][tid & 7] = w2;
  }
  const h16* plane = (typ == 0) ? (Qb + (size_t)head * 8 * N_PIX)
                                : (KV + (size_t)((typ == 2 ? 512 : 0) + head * 8) * N_PIX);
  h16* sflat = &sin_[0][0][0];

  auto stageChunk = [&](int id) {   // id in [0,1600): [ch][row][c6]
    const int ch  = id / 200;
    const int rem = id - ch * 200;
    const int row = rem / 10;
    const int c6  = rem - row * 10;
    const int gy  = ty0 + row - 2;
    const int gx  = tx0 + c6 * 8 - 8;
    const bool ok = ((unsigned)gy < 128u) && ((unsigned)gx < 128u);
    const h16* src = ok ? (plane + (size_t)ch * N_PIX + gy * 128 + gx) : zp;
    gload16(src, sflat + (size_t)id * 8);
  };

  for (int base = wid * 64; base < 832; base += 256) stageChunk(base + lane);
  __syncthreads();  // drains pass-1 DMA (+ weight stores)
  for (int base = 832 + wid * 64; base < 1600; base += 256) stageChunk(base + lane);

  const int px4 = (tid & 15) * 4, py = tid >> 4;
  h16x2 dwa[8][2];

  auto dwCh = [&](int ch) {
    h16x2 A0 = 0, A1 = 0;
#pragma unroll
    for (int di = 0; di < 5; ++di) {
      const uint2 w0 = *(const uint2*)&sin_[ch][py + di][px4 + 4];
      const uint2 w1 = *(const uint2*)&sin_[ch][py + di][px4 + 8];
      const uint2 w2v = *(const uint2*)&sin_[ch][py + di][px4 + 12];
      const unsigned u1 = w0.y, u2 = w1.x, u3 = w1.y, u4 = w2v.x;
      const h16x2 P2 = __builtin_bit_cast(h16x2, u1);
      const h16x2 P3 = __builtin_bit_cast(h16x2, (u2 << 16) | (u1 >> 16));
      const h16x2 P4 = __builtin_bit_cast(h16x2, u2);
      const h16x2 P5 = __builtin_bit_cast(h16x2, (u3 << 16) | (u2 >> 16));
      const h16x2 P6 = __builtin_bit_cast(h16x2, u3);
      const h16x2 P7 = __builtin_bit_cast(h16x2, (u4 << 16) | (u3 >> 16));
      const h16x2 P8 = __builtin_bit_cast(h16x2, u4);
      h16x2 wd;
      wd = swd2[ch][di * 5 + 0]; A0 += wd * P2; A1 += wd * P4;
      wd = swd2[ch][di * 5 + 1]; A0 += wd * P3; A1 += wd * P5;
      wd = swd2[ch][di * 5 + 2]; A0 += wd * P4; A1 += wd * P6;
      wd = swd2[ch][di * 5 + 3]; A0 += wd * P5; A1 += wd * P7;
      wd = swd2[ch][di * 5 + 4]; A0 += wd * P6; A1 += wd * P8;
    }
    dwa[ch][0] = A0; dwa[ch][1] = A1;
  };

#pragma unroll
  for (int ch = 0; ch < 4; ++ch) dwCh(ch);   // overlaps pass-2 DMA
  __syncthreads();  // drains pass-2 DMA
#pragma unroll
  for (int ch = 4; ch < 8; ++ch) dwCh(ch);

#pragma unroll
  for (int oc = 0; oc < 8; ++oc) {
    h16x2 o0 = 0, o1 = 0;
#pragma unroll
    for (int ic = 0; ic < 8; ++ic) {
      const h16x2 w = swp2[oc][ic];
      o0 += w * dwa[ic][0];
      o1 += w * dwa[ic][1];
    }
    h16x4 ov; ov[0] = o0[0]; ov[1] = o0[1]; ov[2] = o1[0]; ov[3] = o1[1];
    *(h16x4*)&y[(size_t)(8 * g + oc) * N_PIX + (ty0 + py) * 128 + tx0 + px4] = ov;
  }
}

// ---------------- K3a: per-slice partial vk[d][e] = sum_n v_d * relu(k_e) (+ k-sum row) ----------------
__global__ __launch_bounds__(256)
void vk_partial_kernel(const h16* __restrict__ KV, const h16* __restrict__ yb,
                       float* __restrict__ part) {
  const int h = blockIdx.y, s = blockIdx.x;
  const h16 *kb, *vb;
  if (h < 64) {
    kb = KV + (size_t)(h * 8) * N_PIX;
    vb = KV + (size_t)(512 + h * 8) * N_PIX;
  } else {
    kb = yb + (size_t)(24 * (h - 64) + 8) * N_PIX;
    vb = yb + (size_t)(24 * (h - 64) + 16) * N_PIX;
  }
  float a[8][8] = {};
  float ak[8] = {};
  const int p0 = s * 2048 + (int)threadIdx.x * 8;
  float kq[8][8], vq[8][8];
#pragma unroll
  for (int e = 0; e < 8; ++e) {
    h16x8 kk = *(const h16x8*)&kb[(size_t)e * N_PIX + p0];
#pragma unroll
    for (int u = 0; u < 8; ++u) kq[e][u] = fmaxf(0.f, (float)kk[u]);
  }
#pragma unroll
  for (int d = 0; d < 8; ++d) {
    h16x8 vv = *(const h16x8*)&vb[(size_t)d * N_PIX + p0];
#pragma unroll
    for (int u = 0; u < 8; ++u) vq[d][u] = (float)vv[u];
  }
#pragma unroll
  for (int d = 0; d < 8; ++d)
#pragma unroll
    for (int e = 0; e < 8; ++e)
#pragma unroll
      for (int u = 0; u < 8; ++u) a[d][e] += vq[d][u] * kq[e][u];
#pragma unroll
  for (int e = 0; e < 8; ++e)
#pragma unroll
    for (int u = 0; u < 8; ++u) ak[e] += kq[e][u];

  __shared__ float red[4][72];
  const int lane = threadIdx.x & 63, wid = threadIdx.x >> 6;
#pragma unroll
  for (int i = 0; i < 72; ++i) {
    float v = (i < 64) ? a[i >> 3][i & 7] : ak[i - 64];
    v += __shfl_xor(v, 32); v += __shfl_xor(v, 16); v += __shfl_xor(v, 8);
    v += __shfl_xor(v, 4);  v += __shfl_xor(v, 2);  v += __shfl_xor(v, 1);
    if (lane == 0) red[wid][i] = v;
  }
  __syncthreads();
  if (threadIdx.x < 72) {
    const float sum_ = red[0][threadIdx.x] + red[1][threadIdx.x] + red[2][threadIdx.x] + red[3][threadIdx.x];
    part[((size_t)h * 8 + s) * 72 + threadIdx.x] = sum_;
  }
}

// ---------------- K3b: deterministic reduce of 8 slices ----------------
__global__ __launch_bounds__(128)
void vk_reduce_kernel(const float* __restrict__ part, float* __restrict__ vk) {
  const int h = blockIdx.x;
  const int i = threadIdx.x;
  if (i < 72) {
    float s = 0.f;
#pragma unroll
    for (int t = 0; t < 8; ++t) s += part[((size_t)h * 8 + t) * 72 + i];
    vk[(size_t)h * 72 + i] = s;
  }
}

// ---------------- K3c: W2[m][h*8+e] = sum_d wpb[m][h*8+d] * vk[h][d][e] ----------------
__global__ __launch_bounds__(256)
void w2_kernel(const bf16_t* __restrict__ wpb, const float* __restrict__ vkm,
               bf16_t* __restrict__ W2) {
  const int idx = blockIdx.x * 256 + threadIdx.x;
  const int m = idx >> 10, c = idx & 1023;
  const int h = c >> 3, e = c & 7;
  float s = 0.f;
#pragma unroll
  for (int d = 0; d < 8; ++d)
    s += (float)wpb[(size_t)m * 1024 + h * 8 + d] * vkm[h * 72 + d * 8 + e];
  W2[idx] = (bf16_t)s;
}

// ---------------- K4: qn = relu(q) / den -> qnT bf16 [N][1024]; ak table hoisted, 5 barriers total ----------------
__global__ __launch_bounds__(256)
void qn_kernel(const h16* __restrict__ Qb, const h16* __restrict__ yb,
               const float* __restrict__ vk, bf16_t* __restrict__ qnT) {
  const int n0 = blockIdx.x * 32;
  const int tid = threadIdx.x;
  const int px = tid & 31, hl = tid >> 5;
  __shared__ __align__(16) bf16_t att_s[32 * 512];
  __shared__ float ak_all[128][8];   // 4 KB: denominators for all 128 heads
#pragma unroll
  for (int r = 0; r < 4; ++r) {
    const int i = tid + r * 256;  // 1024 entries
    ak_all[i >> 3][i & 7] = vk[(size_t)(i >> 3) * 72 + 64 + (i & 7)];
  }
  __syncthreads();
  for (int grp = 0; grp < 2; ++grp) {
    for (int hg = 0; hg < 8; ++hg) {   // no barriers: disjoint att_s writes per (px,chunk)
      const int hh = hg * 8 + hl;      // head within half (0..63)
      const int habs = grp * 64 + hh;
      float q[8];
      if (grp == 0) {
        const h16* plane = Qb + (size_t)(hh * 8) * N_PIX + n0 + px;
#pragma unroll
        for (int e = 0; e < 8; ++e) q[e] = fmaxf(0.f, (float)plane[(size_t)e * N_PIX]);
      } else {
        const h16* plane = yb + (size_t)(24 * hh) * N_PIX + n0 + px;
#pragma unroll
        for (int e = 0; e < 8; ++e) q[e] = fmaxf(0.f, (float)plane[(size_t)e * N_PIX]);
      }
      float den = 1e-15f;
#pragma unroll
      for (int e = 0; e < 8; ++e) den += ak_all[habs][e] * q[e];
      const float rden = 1.0f / den;
      bf16x8 r8;
#pragma unroll
      for (int e = 0; e < 8; ++e) r8[e] = (bf16_t)(q[e] * rden);
      const int chunk = hg * 8 + hl;
      *(bf16x8*)&att_s[px * 512 + ((chunk ^ (px & 7)) << 3)] = r8;
    }
    __syncthreads();   // att_s filled
    bf16_t* dst = qnT + (size_t)n0 * 1024 + grp * 512;
    for (int i = tid; i < 2048; i += 256) {
      const int r = i >> 6, cc = i & 63;
      bf16x8 v = *(const bf16x8*)&att_s[r * 512 + (((cc ^ (r & 7))) << 3)];
      *(bf16x8*)&dst[(size_t)r * 1024 + cc * 8] = v;
    }
    __syncthreads();   // write-out done before att_s refilled
  }
}

// ---------------- launch ----------------
extern "C" void kernel_launch(void* const* d_in, const int* in_sizes, int n_in,
                              void* d_out, int out_size, void* d_ws, size_t ws_size,
                              hipStream_t stream) {
  if (ws_size < WS_NEEDED) return;
  const float* x      = (const float*)d_in[0];
  const float* w_qkv  = (const float*)d_in[1];
  const float* w_dw   = (const float*)d_in[2];
  const float* w_pw   = (const float*)d_in[3];
  const float* w_proj = (const float*)d_in[4];
  const float* gam    = (const float*)d_in[5];
  const float* bet    = (const float*)d_in[6];
  const float* mu     = (const float*)d_in[7];
  const float* va     = (const float*)d_in[8];

  char* w = (char*)d_ws;
  h16*    Qb   = (h16*)(w + OFF_QB);
  h16*    KV   = (h16*)(w + OFF_KV);
  h16*    yb   = (h16*)(w + OFF_Y);
  h16*    xT   = (h16*)(w + OFF_XT);    // aliased with qnT (dead after fix)
  h16*    xTl  = (h16*)(w + OFF_XTL);
  bf16_t* qnT  = (bf16_t*)(w + OFF_ATT);
  h16*    wall = (h16*)(w + OFF_WALL);
  bf16_t* wpb  = (bf16_t*)(w + OFF_WP);
  bf16_t* W2   = (bf16_t*)(w + OFF_W2);
  float*  vk   = (float*)(w + OFF_VK);
  float*  part = (float*)(w + OFF_VKP);
  float*  bna  = (float*)(w + OFF_BNA);
  float*  zp   = (float*)(w + OFF_ZP);

  dim3 blk(256);
  prep_kernel<<<dim3((PREP_TOT + 255) / 256), blk, 0, stream>>>(
      w_qkv, w_proj, gam, bet, mu, va, wall, wpb, bna, zp);

  for (int b = 0; b < 2; ++b) {
    const float* xb = x + (size_t)b * 512 * N_PIX;
    float* outb = (float*)d_out + (size_t)b * 512 * N_PIX;
    // K0a: x -> xT (f16) + xT_lo (residual f16)
    xpose_kernel<<<dim3(512, 16), blk, 0, stream>>>(xb, xT, xTl);
    // K1: unified qkv GEMM (f16 MFMA, K=512, 128x256 tile) -> Qb/KV
    gemm_qkv_kernel<<<dim3(64, 12), blk, 0, stream>>>(wall, xT, Qb, KV);
    // K1b: knife-edge detect + wave-parallel exact in-place repair of Qb
    fix_kernel<<<dim3(64, 64), blk, 0, stream>>>(w_qkv, xT, xTl, Qb);
    // K2: fused dw 5x5 + grouped pw -> y f16 (channel-split pipeline, XCD remap)
    dwpw_kernel<<<dim3(16, 192), blk, 0, stream>>>(Qb, KV, w_dw, w_pw, (const h16*)zp, yb);
    // K3: vk accumulation + W2 fold
    vk_partial_kernel<<<dim3(8, 128), blk, 0, stream>>>(KV, yb, part);
    vk_reduce_kernel<<<dim3(128), dim3(128), 0, stream>>>(part, vk);
    w2_kernel<<<dim3(512 * 1024 / 256), blk, 0, stream>>>(wpb, vk, W2);
    // K4: qn = relu(Qb)/den -> qnT
    qn_kernel<<<dim3(512), blk, 0, stream>>>(Qb, yb, vk, qnT);
    // K5: out = W2 x qnT + bna (128x128 tile)
    gemm_proj_kernel<<<dim3(128, 4), blk, 0, stream>>>(W2, qnT, outb, bna);
  }
}

// Round 17
// 324.222 us; speedup vs baseline: 1.2609x; 1.2609x over previous
//
#include <hip/hip_runtime.h>

typedef __bf16 bf16_t;
typedef __bf16 bf16x8 __attribute__((ext_vector_type(8)));
typedef float  f32x4  __attribute__((ext_vector_type(4)));
typedef _Float16 h16;
typedef _Float16 h16x2 __attribute__((ext_vector_type(2)));
typedef _Float16 h16x4 __attribute__((ext_vector_type(4)));
typedef _Float16 h16x8 __attribute__((ext_vector_type(8)));

#define DEVINL __device__ __forceinline__

static constexpr size_t N_PIX = 16384;
static constexpr float  FIX_TAU = 2.5e-3f;

// ---------------- per-batch workspace layout (bytes) ----------------
static constexpr size_t OFF_QB  = 0;                                   // Qb f16 [512][N] (pre-relu; flagged pixels repaired exact in-place)
static constexpr size_t SZ_QB   = (size_t)512 * N_PIX * 2;
static constexpr size_t OFF_KV  = OFF_QB + SZ_QB;                      // KV f16 [1024][N]
static constexpr size_t SZ_KV   = (size_t)1024 * N_PIX * 2;
static constexpr size_t OFF_Y   = OFF_KV + SZ_KV;                      // y f16 [1536][N]
static constexpr size_t SZ_Y    = (size_t)1536 * N_PIX * 2;
static constexpr size_t OFF_ATT = OFF_Y + SZ_Y;                        // qnT bf16 [N][1024]; xT/xTl f16 aliased
static constexpr size_t SZ_ATT  = (size_t)N_PIX * 1024 * 2;
static constexpr size_t OFF_XT  = OFF_ATT;                             // xT f16 [N][512] (dead after fix; qn overwrites)
static constexpr size_t OFF_XTL = OFF_ATT + (size_t)N_PIX * 512 * 2;   // xT_lo f16 [N][512] (residual)
static constexpr size_t OFF_WALL= OFF_ATT + SZ_ATT;                    // wall f16 [1536][512]: q | k | v (head-major 8-row groups)
static constexpr size_t SZ_WALL = (size_t)1536 * 512 * 2;
static constexpr size_t OFF_WP  = OFF_WALL + SZ_WALL;                  // wpb bf16 [512][1024], pre-scaled by bn inv
static constexpr size_t SZ_WP   = (size_t)512 * 1024 * 2;
static constexpr size_t OFF_VK  = OFF_WP + SZ_WP;                      // vk f32 [128][72]
static constexpr size_t SZ_VK   = (size_t)128 * 72 * 4;
static constexpr size_t OFF_VKP = OFF_VK + SZ_VK;                      // vk partials f32 [128][8][72]
static constexpr size_t SZ_VKP  = (size_t)128 * 8 * 72 * 4;
static constexpr size_t OFF_BNA = OFF_VKP + SZ_VKP;                    // f32[512]
static constexpr size_t OFF_ZP  = OFF_BNA + 2048;                      // 64B zero page
static constexpr size_t OFF_W2  = OFF_ZP + 64;                         // W2 bf16 [512][1024]
static constexpr size_t SZ_W2   = (size_t)512 * 1024 * 2;
static constexpr size_t WS_NEEDED = OFF_W2 + SZ_W2;                    // ~139 MB

// ---------------- helpers ----------------
DEVINL void gload16(const void* g, void* l) {
  __builtin_amdgcn_global_load_lds((const __attribute__((address_space(1))) void*)g,
                                   (__attribute__((address_space(3))) void*)l, 16, 0, 0);
}

// ---------------- K0a: transpose x (f32 [512][N]) -> xT / xT_lo (f16 [N][512]) ----------------
__global__ __launch_bounds__(256)
void xpose_kernel(const float* __restrict__ x, h16* __restrict__ xT, h16* __restrict__ xTl) {
  __shared__ float t[32][33];
  const int n0 = blockIdx.x * 32, c0 = blockIdx.y * 32;
  const int tx = threadIdx.x & 31, ty = threadIdx.x >> 5;
#pragma unroll
  for (int r = 0; r < 4; ++r)
    t[ty + r * 8][tx] = x[(size_t)(c0 + ty + r * 8) * N_PIX + n0 + tx];  // t[c][n]
  __syncthreads();
  const int nl = threadIdx.x >> 3, sub = threadIdx.x & 7;
  const int c8 = (sub & 3) * 8, plane = sub >> 2;
  h16x8 o;
#pragma unroll
  for (int k = 0; k < 8; ++k) {
    const float v = t[c8 + k][nl];
    if (plane == 0) {
      o[k] = (h16)v;
    } else {
      const h16 hi = (h16)v;
      o[k] = (h16)(v - (float)hi);
    }
  }
  h16* dst = plane ? xTl : xT;
  *(h16x8*)&dst[(size_t)(n0 + nl) * 512 + c0 + c8] = o;
}

// ---------------- K0b: build wall f16, scaled wpb, bna, zero page ----------------
static constexpr int PREP_P1 = 1536 * 512;           // wall
static constexpr int PREP_P2 = 512 * 1024;           // wpb
static constexpr int PREP_TOT = PREP_P1 + PREP_P2 + 512 + 16;
__global__ __launch_bounds__(256)
void prep_kernel(const float* __restrict__ wq, const float* __restrict__ wp,
                 const float* __restrict__ gam, const float* __restrict__ bet,
                 const float* __restrict__ mu, const float* __restrict__ va,
                 h16* __restrict__ wall, bf16_t* __restrict__ wpb,
                 float* __restrict__ bna, float* __restrict__ zp) {
  const int i = blockIdx.x * 256 + threadIdx.x;
  if (i < PREP_P1) {
    const int r = i >> 9, c = i & 511;
    int o;
    if (r < 512)       o = (r >> 3) * 24 + (r & 7);               // q
    else if (r < 1024) o = ((r - 512) >> 3) * 24 + 8 + (r & 7);   // k
    else               o = ((r - 1024) >> 3) * 24 + 16 + (r & 7); // v
    wall[i] = (h16)wq[(size_t)o * 512 + c];
  } else if (i < PREP_P1 + PREP_P2) {
    const int j = i - PREP_P1;
    const int m = j >> 10;
    const float inv = gam[m] / sqrtf(va[m] + 1e-5f);
    wpb[j] = (bf16_t)(wp[j] * inv);
  } else if (i < PREP_P1 + PREP_P2 + 512) {
    const int k = i - PREP_P1 - PREP_P2;
    const float inv = gam[k] / sqrtf(va[k] + 1e-5f);
    bna[k] = bet[k] - mu[k] * inv;
  } else if (i < PREP_TOT) {
    zp[i - (PREP_P1 + PREP_P2 + 512)] = 0.f;
  }
}

// ---------------- K1: unified qkv GEMM, f16 MFMA, 128x256 tile, BK=64, swizzled LDS ----------------
// NOTE: launch_bounds(256,2) — (256,3) forces VGPR<=85 and spills acc[4][8] (round-16 regression).
__global__ __launch_bounds__(256, 2)
void gemm_qkv_kernel(const h16* __restrict__ wall, const h16* __restrict__ xT,
                     h16* __restrict__ Qb, h16* __restrict__ KV) {
  __shared__ __align__(16) h16 As[128 * 64];   // 16 KB
  __shared__ __align__(16) h16 Bs[256 * 64];   // 32 KB
  const int tid = threadIdx.x, wid = tid >> 6, lane = tid & 63;
  const int fr = lane & 15, fg = lane >> 4;
  const int wm = (wid >> 1) * 64, wn = (wid & 1) * 128;
  const int by = blockIdx.y;
  const bool isQ = by < 4;
  const int m0 = (isQ ? by : by - 4) * 128;
  const int n0 = blockIdx.x * 256;
  const h16* Aptr = wall + (size_t)by * 128 * 512;

  f32x4 acc[4][8] = {};

  for (int kk = 0; kk < 512; kk += 64) {
    __syncthreads();  // prev iter's LDS reads done
#pragma unroll
    for (int r = 0; r < 4; ++r) {
      const int c = wid * 64 + lane + 256 * r;
      const int row = c >> 3, cc = c & 7;
      gload16(Aptr + (size_t)row * 512 + kk + ((cc ^ (row & 7)) * 8),
              As + (size_t)(wid * 64 + 256 * r) * 8);
    }
#pragma unroll
    for (int r = 0; r < 8; ++r) {
      const int c = wid * 64 + lane + 256 * r;
      const int row = c >> 3, cc = c & 7;
      gload16(xT + (size_t)(n0 + row) * 512 + kk + ((cc ^ (row & 7)) * 8),
              Bs + (size_t)(wid * 64 + 256 * r) * 8);
    }
    __syncthreads();  // drains vmcnt(0)
#pragma unroll
    for (int ks = 0; ks < 2; ++ks) {
      h16x8 af[4], bfr[8];
#pragma unroll
      for (int i = 0; i < 4; ++i)
        af[i]  = *(const h16x8*)&As[(wm + i * 16 + fr) * 64 + (((ks * 4 + fg) ^ (fr & 7)) * 8)];
#pragma unroll
      for (int j = 0; j < 8; ++j)
        bfr[j] = *(const h16x8*)&Bs[(wn + j * 16 + fr) * 64 + (((ks * 4 + fg) ^ (fr & 7)) * 8)];
#pragma unroll
      for (int i = 0; i < 4; ++i)
#pragma unroll
        for (int j = 0; j < 8; ++j)
          acc[i][j] = __builtin_amdgcn_mfma_f32_16x16x32_f16(af[i], bfr[j], acc[i][j], 0, 0, 0);
    }
  }

#pragma unroll
  for (int i = 0; i < 4; ++i)
#pragma unroll
    for (int r = 0; r < 4; ++r) {
      const int m = m0 + wm + i * 16 + fg * 4 + r;
      h16* dst = isQ ? Qb : KV;
#pragma unroll
      for (int j = 0; j < 8; ++j) {
        const int n = n0 + wn + j * 16 + fr;
        dst[(size_t)m * N_PIX + n] = (h16)acc[i][j][r];
      }
    }
}

// ---------------- K1b: knife-edge detect + wave-parallel exact IN-PLACE repair of Qb ----------------
__global__ __launch_bounds__(256)
void fix_kernel(const float* __restrict__ wq, const h16* __restrict__ xT,
                const h16* __restrict__ xTl, h16* __restrict__ Qb) {
  const int h = blockIdx.y;
  const int n = blockIdx.x * 256 + threadIdx.x;
  const int lane = threadIdx.x & 63;
  float mx = 0.f;
#pragma unroll
  for (int e = 0; e < 8; ++e)
    mx = fmaxf(mx, (float)Qb[(size_t)(h * 8 + e) * N_PIX + n]);
  unsigned long long mask = __ballot(mx < FIX_TAU);  // wave-uniform
  const int cb = blockIdx.x * 256 + ((int)threadIdx.x & ~63);  // wave's chunk base
  while (mask) {
    const int bit = __builtin_ctzll(mask);
    mask &= mask - 1;
    const int np = cb + bit;
    const int c0 = lane * 8;
    const h16x8 xh = *(const h16x8*)&xT[(size_t)np * 512 + c0];
    const h16x8 xl = *(const h16x8*)&xTl[(size_t)np * 512 + c0];
    float xs[8];
#pragma unroll
    for (int u = 0; u < 8; ++u) xs[u] = (float)xh[u] + (float)xl[u];
    float acc[8];
#pragma unroll
    for (int e = 0; e < 8; ++e) {
      const float4 w0 = *(const float4*)&wq[(size_t)(h * 24 + e) * 512 + c0];
      const float4 w1 = *(const float4*)&wq[(size_t)(h * 24 + e) * 512 + c0 + 4];
      acc[e] = w0.x * xs[0] + w0.y * xs[1] + w0.z * xs[2] + w0.w * xs[3]
             + w1.x * xs[4] + w1.y * xs[5] + w1.z * xs[6] + w1.w * xs[7];
    }
#pragma unroll
    for (int e = 0; e < 8; ++e) {
      acc[e] += __shfl_xor(acc[e], 32); acc[e] += __shfl_xor(acc[e], 16);
      acc[e] += __shfl_xor(acc[e], 8);  acc[e] += __shfl_xor(acc[e], 4);
      acc[e] += __shfl_xor(acc[e], 2);  acc[e] += __shfl_xor(acc[e], 1);
    }
    if (lane < 8) {
      float v = acc[0];
#pragma unroll
      for (int e = 1; e < 8; ++e) if (lane == e) v = acc[e];  // compile-time indices
      Qb[(size_t)(h * 8 + lane) * N_PIX + np] = (h16)v;       // exact pre-relu value
    }
  }
}

// ---------------- K5: proj GEMM out = W2 x qnT + bna, 128x128 tile, BK=64, swizzled ----------------
__global__ __launch_bounds__(256, 4)
void gemm_proj_kernel(const bf16_t* __restrict__ A, const bf16_t* __restrict__ B,
                      float* __restrict__ Cout, const float* __restrict__ bna) {
  __shared__ __align__(16) bf16_t As[128 * 64];
  __shared__ __align__(16) bf16_t Bs[128 * 64];
  const int tid = threadIdx.x, wid = tid >> 6, lane = tid & 63;
  const int fr = lane & 15, fg = lane >> 4;
  const int wm = (wid >> 1) * 64, wn = (wid & 1) * 64;
  const int m0 = blockIdx.y * 128, n0 = blockIdx.x * 128;
  const int srow = tid >> 3;
  const int soff = (((tid & 7) ^ (srow & 7)) * 8);
  const bf16_t* Ab = A + (size_t)m0 * 1024;
  const bf16_t* Bb = B + (size_t)n0 * 1024;

  f32x4 acc[4][4] = {};

  for (int kk = 0; kk < 1024; kk += 64) {
    __syncthreads();
#pragma unroll
    for (int r = 0; r < 4; ++r) {
      gload16(Ab + (size_t)(srow + 32 * r) * 1024 + kk + soff, As + (wid * 8 + 32 * r) * 64);
      gload16(Bb + (size_t)(srow + 32 * r) * 1024 + kk + soff, Bs + (wid * 8 + 32 * r) * 64);
    }
    __syncthreads();
#pragma unroll
    for (int ks = 0; ks < 2; ++ks) {
      bf16x8 af[4], bfr[4];
#pragma unroll
      for (int i = 0; i < 4; ++i)
        af[i]  = *(const bf16x8*)&As[(wm + i * 16 + fr) * 64 + (((ks * 4 + fg) ^ (fr & 7)) * 8)];
#pragma unroll
      for (int j = 0; j < 4; ++j)
        bfr[j] = *(const bf16x8*)&Bs[(wn + j * 16 + fr) * 64 + (((ks * 4 + fg) ^ (fr & 7)) * 8)];
#pragma unroll
      for (int i = 0; i < 4; ++i)
#pragma unroll
        for (int j = 0; j < 4; ++j)
          acc[i][j] = __builtin_amdgcn_mfma_f32_16x16x32_bf16(af[i], bfr[j], acc[i][j], 0, 0, 0);
    }
  }

#pragma unroll
  for (int i = 0; i < 4; ++i)
#pragma unroll
    for (int r = 0; r < 4; ++r) {
      const int m = m0 + wm + i * 16 + fg * 4 + r;
      const float sh = bna[m];
#pragma unroll
      for (int j = 0; j < 4; ++j)
        Cout[(size_t)m * N_PIX + n0 + wn + j * 16 + fr] = acc[i][j][r] + sh;
    }
}

// ---------------- K2: fused dw 5x5 + grouped 1x1; channel-split async pipeline, XCD-remapped ----------------
__global__ __launch_bounds__(256)
void dwpw_kernel(const h16* __restrict__ Qb, const h16* __restrict__ KV,
                 const float* __restrict__ wdw, const float* __restrict__ wpw,
                 const h16* __restrict__ zp, h16* __restrict__ y) {
  const int bidHW = blockIdx.x + (blockIdx.y << 4);          // gridDim = (16,192)
  const int work  = (bidHW & 7) * 384 + (bidHW >> 3);
  const int g = work >> 4, t = work & 15;
  const int typ = g % 3, head = g / 3;
  const int ty0 = (t >> 1) * 16, tx0 = (t & 1) * 64;
  const int tid = threadIdx.x, wid = tid >> 6, lane = tid & 63;
  __shared__ __align__(16) h16 sin_[8][20][80];
  __shared__ h16x2 swd2[8][25];
  __shared__ h16x2 swp2[8][8];
  if (tid < 200) {
    const h16 w = (h16)wdw[(g * 8 + tid / 25) * 25 + tid % 25];
    h16x2 w2; w2[0] = w; w2[1] = w;
    swd2[tid / 25][tid % 25] = w2;
  }
  if (tid < 64) {
    const h16 w = (h16)wpw[(g * 8 + (tid >> 3)) * 8 + (tid & 7)];
    h16x2 w2; w2[0] = w; w2[1] = w;
    swp2[tid >> 3][tid & 7] = w2;
  }
  const h16* plane = (typ == 0) ? (Qb + (size_t)head * 8 * N_PIX)
                                : (KV + (size_t)((typ == 2 ? 512 : 0) + head * 8) * N_PIX);
  h16* sflat = &sin_[0][0][0];

  auto stageChunk = [&](int id) {   // id in [0,1600): [ch][row][c6]
    const int ch  = id / 200;
    const int rem = id - ch * 200;
    const int row = rem / 10;
    const int c6  = rem - row * 10;
    const int gy  = ty0 + row - 2;
    const int gx  = tx0 + c6 * 8 - 8;
    const bool ok = ((unsigned)gy < 128u) && ((unsigned)gx < 128u);
    const h16* src = ok ? (plane + (size_t)ch * N_PIX + gy * 128 + gx) : zp;
    gload16(src, sflat + (size_t)id * 8);
  };

  for (int base = wid * 64; base < 832; base += 256) stageChunk(base + lane);
  __syncthreads();  // drains pass-1 DMA (+ weight stores)
  for (int base = 832 + wid * 64; base < 1600; base += 256) stageChunk(base + lane);

  const int px4 = (tid & 15) * 4, py = tid >> 4;
  h16x2 dwa[8][2];

  auto dwCh = [&](int ch) {
    h16x2 A0 = 0, A1 = 0;
#pragma unroll
    for (int di = 0; di < 5; ++di) {
      const uint2 w0 = *(const uint2*)&sin_[ch][py + di][px4 + 4];
      const uint2 w1 = *(const uint2*)&sin_[ch][py + di][px4 + 8];
      const uint2 w2v = *(const uint2*)&sin_[ch][py + di][px4 + 12];
      const unsigned u1 = w0.y, u2 = w1.x, u3 = w1.y, u4 = w2v.x;
      const h16x2 P2 = __builtin_bit_cast(h16x2, u1);
      const h16x2 P3 = __builtin_bit_cast(h16x2, (u2 << 16) | (u1 >> 16));
      const h16x2 P4 = __builtin_bit_cast(h16x2, u2);
      const h16x2 P5 = __builtin_bit_cast(h16x2, (u3 << 16) | (u2 >> 16));
      const h16x2 P6 = __builtin_bit_cast(h16x2, u3);
      const h16x2 P7 = __builtin_bit_cast(h16x2, (u4 << 16) | (u3 >> 16));
      const h16x2 P8 = __builtin_bit_cast(h16x2, u4);
      h16x2 wd;
      wd = swd2[ch][di * 5 + 0]; A0 += wd * P2; A1 += wd * P4;
      wd = swd2[ch][di * 5 + 1]; A0 += wd * P3; A1 += wd * P5;
      wd = swd2[ch][di * 5 + 2]; A0 += wd * P4; A1 += wd * P6;
      wd = swd2[ch][di * 5 + 3]; A0 += wd * P5; A1 += wd * P7;
      wd = swd2[ch][di * 5 + 4]; A0 += wd * P6; A1 += wd * P8;
    }
    dwa[ch][0] = A0; dwa[ch][1] = A1;
  };

#pragma unroll
  for (int ch = 0; ch < 4; ++ch) dwCh(ch);   // overlaps pass-2 DMA
  __syncthreads();  // drains pass-2 DMA
#pragma unroll
  for (int ch = 4; ch < 8; ++ch) dwCh(ch);

#pragma unroll
  for (int oc = 0; oc < 8; ++oc) {
    h16x2 o0 = 0, o1 = 0;
#pragma unroll
    for (int ic = 0; ic < 8; ++ic) {
      const h16x2 w = swp2[oc][ic];
      o0 += w * dwa[ic][0];
      o1 += w * dwa[ic][1];
    }
    h16x4 ov; ov[0] = o0[0]; ov[1] = o0[1]; ov[2] = o1[0]; ov[3] = o1[1];
    *(h16x4*)&y[(size_t)(8 * g + oc) * N_PIX + (ty0 + py) * 128 + tx0 + px4] = ov;
  }
}

// ---------------- K3a: per-slice partial vk[d][e] = sum_n v_d * relu(k_e) (+ k-sum row) ----------------
__global__ __launch_bounds__(256)
void vk_partial_kernel(const h16* __restrict__ KV, const h16* __restrict__ yb,
                       float* __restrict__ part) {
  const int h = blockIdx.y, s = blockIdx.x;
  const h16 *kb, *vb;
  if (h < 64) {
    kb = KV + (size_t)(h * 8) * N_PIX;
    vb = KV + (size_t)(512 + h * 8) * N_PIX;
  } else {
    kb = yb + (size_t)(24 * (h - 64) + 8) * N_PIX;
    vb = yb + (size_t)(24 * (h - 64) + 16) * N_PIX;
  }
  float a[8][8] = {};
  float ak[8] = {};
  const int p0 = s * 2048 + (int)threadIdx.x * 8;
  float kq[8][8], vq[8][8];
#pragma unroll
  for (int e = 0; e < 8; ++e) {
    h16x8 kk = *(const h16x8*)&kb[(size_t)e * N_PIX + p0];
#pragma unroll
    for (int u = 0; u < 8; ++u) kq[e][u] = fmaxf(0.f, (float)kk[u]);
  }
#pragma unroll
  for (int d = 0; d < 8; ++d) {
    h16x8 vv = *(const h16x8*)&vb[(size_t)d * N_PIX + p0];
#pragma unroll
    for (int u = 0; u < 8; ++u) vq[d][u] = (float)vv[u];
  }
#pragma unroll
  for (int d = 0; d < 8; ++d)
#pragma unroll
    for (int e = 0; e < 8; ++e)
#pragma unroll
      for (int u = 0; u < 8; ++u) a[d][e] += vq[d][u] * kq[e][u];
#pragma unroll
  for (int e = 0; e < 8; ++e)
#pragma unroll
    for (int u = 0; u < 8; ++u) ak[e] += kq[e][u];

  __shared__ float red[4][72];
  const int lane = threadIdx.x & 63, wid = threadIdx.x >> 6;
#pragma unroll
  for (int i = 0; i < 72; ++i) {
    float v = (i < 64) ? a[i >> 3][i & 7] : ak[i - 64];
    v += __shfl_xor(v, 32); v += __shfl_xor(v, 16); v += __shfl_xor(v, 8);
    v += __shfl_xor(v, 4);  v += __shfl_xor(v, 2);  v += __shfl_xor(v, 1);
    if (lane == 0) red[wid][i] = v;
  }
  __syncthreads();
  if (threadIdx.x < 72) {
    const float sum_ = red[0][threadIdx.x] + red[1][threadIdx.x] + red[2][threadIdx.x] + red[3][threadIdx.x];
    part[((size_t)h * 8 + s) * 72 + threadIdx.x] = sum_;
  }
}

// ---------------- K3b: deterministic reduce of 8 slices ----------------
__global__ __launch_bounds__(128)
void vk_reduce_kernel(const float* __restrict__ part, float* __restrict__ vk) {
  const int h = blockIdx.x;
  const int i = threadIdx.x;
  if (i < 72) {
    float s = 0.f;
#pragma unroll
    for (int t = 0; t < 8; ++t) s += part[((size_t)h * 8 + t) * 72 + i];
    vk[(size_t)h * 72 + i] = s;
  }
}

// ---------------- K3c: W2[m][h*8+e] = sum_d wpb[m][h*8+d] * vk[h][d][e] ----------------
__global__ __launch_bounds__(256)
void w2_kernel(const bf16_t* __restrict__ wpb, const float* __restrict__ vkm,
               bf16_t* __restrict__ W2) {
  const int idx = blockIdx.x * 256 + threadIdx.x;
  const int m = idx >> 10, c = idx & 1023;
  const int h = c >> 3, e = c & 7;
  float s = 0.f;
#pragma unroll
  for (int d = 0; d < 8; ++d)
    s += (float)wpb[(size_t)m * 1024 + h * 8 + d] * vkm[h * 72 + d * 8 + e];
  W2[idx] = (bf16_t)s;
}

// ---------------- K4: qn = relu(q) / den -> qnT bf16 [N][1024]; ak table hoisted, 5 barriers total ----------------
__global__ __launch_bounds__(256)
void qn_kernel(const h16* __restrict__ Qb, const h16* __restrict__ yb,
               const float* __restrict__ vk, bf16_t* __restrict__ qnT) {
  const int n0 = blockIdx.x * 32;
  const int tid = threadIdx.x;
  const int px = tid & 31, hl = tid >> 5;
  __shared__ __align__(16) bf16_t att_s[32 * 512];
  __shared__ float ak_all[128][8];   // 4 KB: denominators for all 128 heads
#pragma unroll
  for (int r = 0; r < 4; ++r) {
    const int i = tid + r * 256;  // 1024 entries
    ak_all[i >> 3][i & 7] = vk[(size_t)(i >> 3) * 72 + 64 + (i & 7)];
  }
  __syncthreads();
  for (int grp = 0; grp < 2; ++grp) {
    for (int hg = 0; hg < 8; ++hg) {   // no barriers: disjoint att_s writes per (px,chunk)
      const int hh = hg * 8 + hl;      // head within half (0..63)
      const int habs = grp * 64 + hh;
      float q[8];
      if (grp == 0) {
        const h16* plane = Qb + (size_t)(hh * 8) * N_PIX + n0 + px;
#pragma unroll
        for (int e = 0; e < 8; ++e) q[e] = fmaxf(0.f, (float)plane[(size_t)e * N_PIX]);
      } else {
        const h16* plane = yb + (size_t)(24 * hh) * N_PIX + n0 + px;
#pragma unroll
        for (int e = 0; e < 8; ++e) q[e] = fmaxf(0.f, (float)plane[(size_t)e * N_PIX]);
      }
      float den = 1e-15f;
#pragma unroll
      for (int e = 0; e < 8; ++e) den += ak_all[habs][e] * q[e];
      const float rden = 1.0f / den;
      bf16x8 r8;
#pragma unroll
      for (int e = 0; e < 8; ++e) r8[e] = (bf16_t)(q[e] * rden);
      const int chunk = hg * 8 + hl;
      *(bf16x8*)&att_s[px * 512 + ((chunk ^ (px & 7)) << 3)] = r8;
    }
    __syncthreads();   // att_s filled
    bf16_t* dst = qnT + (size_t)n0 * 1024 + grp * 512;
    for (int i = tid; i < 2048; i += 256) {
      const int r = i >> 6, cc = i & 63;
      bf16x8 v = *(const bf16x8*)&att_s[r * 512 + (((cc ^ (r & 7))) << 3)];
      *(bf16x8*)&dst[(size_t)r * 1024 + cc * 8] = v;
    }
    __syncthreads();   // write-out done before att_s refilled
  }
}

// ---------------- launch ----------------
extern "C" void kernel_launch(void* const* d_in, const int* in_sizes, int n_in,
                              void* d_out, int out_size, void* d_ws, size_t ws_size,
                              hipStream_t stream) {
  if (ws_size < WS_NEEDED) return;
  const float* x      = (const float*)d_in[0];
  const float* w_qkv  = (const float*)d_in[1];
  const float* w_dw   = (const float*)d_in[2];
  const float* w_pw   = (const float*)d_in[3];
  const float* w_proj = (const float*)d_in[4];
  const float* gam    = (const float*)d_in[5];
  const float* bet    = (const float*)d_in[6];
  const float* mu     = (const float*)d_in[7];
  const float* va     = (const float*)d_in[8];

  char* w = (char*)d_ws;
  h16*    Qb   = (h16*)(w + OFF_QB);
  h16*    KV   = (h16*)(w + OFF_KV);
  h16*    yb   = (h16*)(w + OFF_Y);
  h16*    xT   = (h16*)(w + OFF_XT);    // aliased with qnT (dead after fix)
  h16*    xTl  = (h16*)(w + OFF_XTL);
  bf16_t* qnT  = (bf16_t*)(w + OFF_ATT);
  h16*    wall = (h16*)(w + OFF_WALL);
  bf16_t* wpb  = (bf16_t*)(w + OFF_WP);
  bf16_t* W2   = (bf16_t*)(w + OFF_W2);
  float*  vk   = (float*)(w + OFF_VK);
  float*  part = (float*)(w + OFF_VKP);
  float*  bna  = (float*)(w + OFF_BNA);
  float*  zp   = (float*)(w + OFF_ZP);

  dim3 blk(256);
  prep_kernel<<<dim3((PREP_TOT + 255) / 256), blk, 0, stream>>>(
      w_qkv, w_proj, gam, bet, mu, va, wall, wpb, bna, zp);

  for (int b = 0; b < 2; ++b) {
    const float* xb = x + (size_t)b * 512 * N_PIX;
    float* outb = (float*)d_out + (size_t)b * 512 * N_PIX;
    // K0a: x -> xT (f16) + xT_lo (residual f16)
    xpose_kernel<<<dim3(512, 16), blk, 0, stream>>>(xb, xT, xTl);
    // K1: unified qkv GEMM (f16 MFMA, K=512, 128x256 tile) -> Qb/KV
    gemm_qkv_kernel<<<dim3(64, 12), blk, 0, stream>>>(wall, xT, Qb, KV);
    // K1b: knife-edge detect + wave-parallel exact in-place repair of Qb
    fix_kernel<<<dim3(64, 64), blk, 0, stream>>>(w_qkv, xT, xTl, Qb);
    // K2: fused dw 5x5 + grouped pw -> y f16 (channel-split pipeline, XCD remap)
    dwpw_kernel<<<dim3(16, 192), blk, 0, stream>>>(Qb, KV, w_dw, w_pw, (const h16*)zp, yb);
    // K3: vk accumulation + W2 fold
    vk_partial_kernel<<<dim3(8, 128), blk, 0, stream>>>(KV, yb, part);
    vk_reduce_kernel<<<dim3(128), dim3(128), 0, stream>>>(part, vk);
    w2_kernel<<<dim3(512 * 1024 / 256), blk, 0, stream>>>(wpb, vk, W2);
    // K4: qn = relu(Qb)/den -> qnT
    qn_kernel<<<dim3(512), blk, 0, stream>>>(Qb, yb, vk, qnT);
    // K5: out = W2 x qnT + bna (128x128 tile)
    gemm_proj_kernel<<<dim3(128, 4), blk, 0, stream>>>(W2, qnT, outb, bna);
  }
}

// Round 18
// 319.702 us; speedup vs baseline: 1.2787x; 1.0141x over previous
//
#include <hip/hip_runtime.h>

typedef __bf16 bf16_t;
typedef __bf16 bf16x8 __attribute__((ext_vector_type(8)));
typedef float  f32x4  __attribute__((ext_vector_type(4)));
typedef _Float16 h16;
typedef _Float16 h16x2 __attribute__((ext_vector_type(2)));
typedef _Float16 h16x4 __attribute__((ext_vector_type(4)));
typedef _Float16 h16x8 __attribute__((ext_vector_type(8)));

#define DEVINL __device__ __forceinline__

static constexpr size_t N_PIX = 16384;
static constexpr float  FIX_TAU = 2.5e-3f;

// ---------------- per-batch workspace layout (bytes) ----------------
static constexpr size_t OFF_QB  = 0;                                   // Qb f16 [512][N] (pre-relu; flagged pixels repaired exact in-place)
static constexpr size_t SZ_QB   = (size_t)512 * N_PIX * 2;
static constexpr size_t OFF_KV  = OFF_QB + SZ_QB;                      // KV f16 [1024][N]
static constexpr size_t SZ_KV   = (size_t)1024 * N_PIX * 2;
static constexpr size_t OFF_Y   = OFF_KV + SZ_KV;                      // y f16 [1536][N]
static constexpr size_t SZ_Y    = (size_t)1536 * N_PIX * 2;
static constexpr size_t OFF_ATT = OFF_Y + SZ_Y;                        // qnT bf16 [N][1024]; xT/xTl f16 aliased
static constexpr size_t SZ_ATT  = (size_t)N_PIX * 1024 * 2;
static constexpr size_t OFF_XT  = OFF_ATT;                             // xT f16 [N][512] (dead after fix; qn overwrites)
static constexpr size_t OFF_XTL = OFF_ATT + (size_t)N_PIX * 512 * 2;   // xT_lo f16 [N][512] (residual)
static constexpr size_t OFF_WALL= OFF_ATT + SZ_ATT;                    // wall f16 [1536][512]: q | k | v (head-major 8-row groups)
static constexpr size_t SZ_WALL = (size_t)1536 * 512 * 2;
static constexpr size_t OFF_WP  = OFF_WALL + SZ_WALL;                  // wpb bf16 [512][1024], pre-scaled by bn inv
static constexpr size_t SZ_WP   = (size_t)512 * 1024 * 2;
static constexpr size_t OFF_VK  = OFF_WP + SZ_WP;                      // vk f32 [128][72]
static constexpr size_t SZ_VK   = (size_t)128 * 72 * 4;
static constexpr size_t OFF_VKP = OFF_VK + SZ_VK;                      // vk partials f32 [128][8][72]
static constexpr size_t SZ_VKP  = (size_t)128 * 8 * 72 * 4;
static constexpr size_t OFF_BNA = OFF_VKP + SZ_VKP;                    // f32[512]
static constexpr size_t OFF_ZP  = OFF_BNA + 2048;                      // 64B zero page
static constexpr size_t OFF_W2  = OFF_ZP + 64;                         // W2 bf16 [512][1024]
static constexpr size_t SZ_W2   = (size_t)512 * 1024 * 2;
static constexpr size_t WS_NEEDED = OFF_W2 + SZ_W2;                    // ~139 MB

// ---------------- helpers ----------------
DEVINL void gload16(const void* g, void* l) {
  __builtin_amdgcn_global_load_lds((const __attribute__((address_space(1))) void*)g,
                                   (__attribute__((address_space(3))) void*)l, 16, 0, 0);
}

// ---------------- K0a: transpose x (f32 [512][N]) -> xT / xT_lo (f16 [N][512]) ----------------
__global__ __launch_bounds__(256)
void xpose_kernel(const float* __restrict__ x, h16* __restrict__ xT, h16* __restrict__ xTl) {
  __shared__ float t[32][33];
  const int n0 = blockIdx.x * 32, c0 = blockIdx.y * 32;
  const int tx = threadIdx.x & 31, ty = threadIdx.x >> 5;
#pragma unroll
  for (int r = 0; r < 4; ++r)
    t[ty + r * 8][tx] = x[(size_t)(c0 + ty + r * 8) * N_PIX + n0 + tx];  // t[c][n]
  __syncthreads();
  const int nl = threadIdx.x >> 3, sub = threadIdx.x & 7;
  const int c8 = (sub & 3) * 8, plane = sub >> 2;
  h16x8 o;
#pragma unroll
  for (int k = 0; k < 8; ++k) {
    const float v = t[c8 + k][nl];
    if (plane == 0) {
      o[k] = (h16)v;
    } else {
      const h16 hi = (h16)v;
      o[k] = (h16)(v - (float)hi);
    }
  }
  h16* dst = plane ? xTl : xT;
  *(h16x8*)&dst[(size_t)(n0 + nl) * 512 + c0 + c8] = o;
}

// ---------------- K0b: build wall f16, scaled wpb, bna, zero page ----------------
static constexpr int PREP_P1 = 1536 * 512;           // wall
static constexpr int PREP_P2 = 512 * 1024;           // wpb
static constexpr int PREP_TOT = PREP_P1 + PREP_P2 + 512 + 16;
__global__ __launch_bounds__(256)
void prep_kernel(const float* __restrict__ wq, const float* __restrict__ wp,
                 const float* __restrict__ gam, const float* __restrict__ bet,
                 const float* __restrict__ mu, const float* __restrict__ va,
                 h16* __restrict__ wall, bf16_t* __restrict__ wpb,
                 float* __restrict__ bna, float* __restrict__ zp) {
  const int i = blockIdx.x * 256 + threadIdx.x;
  if (i < PREP_P1) {
    const int r = i >> 9, c = i & 511;
    int o;
    if (r < 512)       o = (r >> 3) * 24 + (r & 7);               // q
    else if (r < 1024) o = ((r - 512) >> 3) * 24 + 8 + (r & 7);   // k
    else               o = ((r - 1024) >> 3) * 24 + 16 + (r & 7); // v
    wall[i] = (h16)wq[(size_t)o * 512 + c];
  } else if (i < PREP_P1 + PREP_P2) {
    const int j = i - PREP_P1;
    const int m = j >> 10;
    const float inv = gam[m] / sqrtf(va[m] + 1e-5f);
    wpb[j] = (bf16_t)(wp[j] * inv);
  } else if (i < PREP_P1 + PREP_P2 + 512) {
    const int k = i - PREP_P1 - PREP_P2;
    const float inv = gam[k] / sqrtf(va[k] + 1e-5f);
    bna[k] = bet[k] - mu[k] * inv;
  } else if (i < PREP_TOT) {
    zp[i - (PREP_P1 + PREP_P2 + 512)] = 0.f;
  }
}

// ---------------- K1: unified qkv GEMM, f16 MFMA, 128x128 tile, BK=64, 2-phase LDS double-buffer ----------------
// stage(t+1) flies during MFMA(t); one barrier per K-step (drains vmcnt(0) + guards buffer reuse).
__global__ __launch_bounds__(256, 2)
void gemm_qkv_kernel(const h16* __restrict__ wall, const h16* __restrict__ xT,
                     h16* __restrict__ Qb, h16* __restrict__ KV) {
  __shared__ __align__(16) h16 As[2][128 * 64];   // 32 KB
  __shared__ __align__(16) h16 Bs[2][128 * 64];   // 32 KB
  const int tid = threadIdx.x, wid = tid >> 6, lane = tid & 63;
  const int fr = lane & 15, fg = lane >> 4;
  const int wm = (wid >> 1) * 64, wn = (wid & 1) * 64;
  const int by = blockIdx.y;
  const bool isQ = by < 4;
  const int m0 = (isQ ? by : by - 4) * 128;
  const int n0 = blockIdx.x * 128;
  const h16* Aptr = wall + (size_t)by * 128 * 512;
  const h16* Bptr = xT + (size_t)n0 * 512;
  const int srow = tid >> 3;                       // 0..31 (LDS row mod 32)
  const int soff = (((tid & 7) ^ (srow & 7)) * 8); // pre-swizzled global chunk

  auto stage = [&](int kk, int buf) {
#pragma unroll
    for (int r = 0; r < 4; ++r) {
      gload16(Aptr + (size_t)(srow + 32 * r) * 512 + kk + soff, &As[buf][(wid * 8 + 32 * r) * 64]);
      gload16(Bptr + (size_t)(srow + 32 * r) * 512 + kk + soff, &Bs[buf][(wid * 8 + 32 * r) * 64]);
    }
  };

  f32x4 acc[4][4] = {};

  stage(0, 0);
  __syncthreads();   // drains vmcnt(0): buf0 ready
  int cur = 0;
  for (int kk = 0; kk < 512; kk += 64) {
    if (kk + 64 < 512) stage(kk + 64, cur ^ 1);   // async: flies during compute below
#pragma unroll
    for (int ks = 0; ks < 2; ++ks) {
      h16x8 af[4], bfr[4];
#pragma unroll
      for (int i = 0; i < 4; ++i)
        af[i]  = *(const h16x8*)&As[cur][(wm + i * 16 + fr) * 64 + (((ks * 4 + fg) ^ (fr & 7)) * 8)];
#pragma unroll
      for (int j = 0; j < 4; ++j)
        bfr[j] = *(const h16x8*)&Bs[cur][(wn + j * 16 + fr) * 64 + (((ks * 4 + fg) ^ (fr & 7)) * 8)];
#pragma unroll
      for (int i = 0; i < 4; ++i)
#pragma unroll
        for (int j = 0; j < 4; ++j)
          acc[i][j] = __builtin_amdgcn_mfma_f32_16x16x32_f16(af[i], bfr[j], acc[i][j], 0, 0, 0);
    }
    __syncthreads();  // drains next-tile DMA; all reads of cur done before overwrite
    cur ^= 1;
  }

#pragma unroll
  for (int i = 0; i < 4; ++i)
#pragma unroll
    for (int r = 0; r < 4; ++r) {
      const int m = m0 + wm + i * 16 + fg * 4 + r;
      h16* dst = isQ ? Qb : KV;
#pragma unroll
      for (int j = 0; j < 4; ++j) {
        const int n = n0 + wn + j * 16 + fr;
        dst[(size_t)m * N_PIX + n] = (h16)acc[i][j][r];
      }
    }
}

// ---------------- K1b: knife-edge detect + wave-parallel exact IN-PLACE repair of Qb ----------------
__global__ __launch_bounds__(256)
void fix_kernel(const float* __restrict__ wq, const h16* __restrict__ xT,
                const h16* __restrict__ xTl, h16* __restrict__ Qb) {
  const int h = blockIdx.y;
  const int n = blockIdx.x * 256 + threadIdx.x;
  const int lane = threadIdx.x & 63;
  float mx = 0.f;
#pragma unroll
  for (int e = 0; e < 8; ++e)
    mx = fmaxf(mx, (float)Qb[(size_t)(h * 8 + e) * N_PIX + n]);
  unsigned long long mask = __ballot(mx < FIX_TAU);  // wave-uniform
  const int cb = blockIdx.x * 256 + ((int)threadIdx.x & ~63);  // wave's chunk base
  while (mask) {
    const int bit = __builtin_ctzll(mask);
    mask &= mask - 1;
    const int np = cb + bit;
    const int c0 = lane * 8;
    const h16x8 xh = *(const h16x8*)&xT[(size_t)np * 512 + c0];
    const h16x8 xl = *(const h16x8*)&xTl[(size_t)np * 512 + c0];
    float xs[8];
#pragma unroll
    for (int u = 0; u < 8; ++u) xs[u] = (float)xh[u] + (float)xl[u];
    float acc[8];
#pragma unroll
    for (int e = 0; e < 8; ++e) {
      const float4 w0 = *(const float4*)&wq[(size_t)(h * 24 + e) * 512 + c0];
      const float4 w1 = *(const float4*)&wq[(size_t)(h * 24 + e) * 512 + c0 + 4];
      acc[e] = w0.x * xs[0] + w0.y * xs[1] + w0.z * xs[2] + w0.w * xs[3]
             + w1.x * xs[4] + w1.y * xs[5] + w1.z * xs[6] + w1.w * xs[7];
    }
#pragma unroll
    for (int e = 0; e < 8; ++e) {
      acc[e] += __shfl_xor(acc[e], 32); acc[e] += __shfl_xor(acc[e], 16);
      acc[e] += __shfl_xor(acc[e], 8);  acc[e] += __shfl_xor(acc[e], 4);
      acc[e] += __shfl_xor(acc[e], 2);  acc[e] += __shfl_xor(acc[e], 1);
    }
    if (lane < 8) {
      float v = acc[0];
#pragma unroll
      for (int e = 1; e < 8; ++e) if (lane == e) v = acc[e];  // compile-time indices
      Qb[(size_t)(h * 8 + lane) * N_PIX + np] = (h16)v;       // exact pre-relu value
    }
  }
}

// ---------------- K5: proj GEMM out = W2 x qnT + bna, 128x128 tile, BK=64, swizzled ----------------
__global__ __launch_bounds__(256, 4)
void gemm_proj_kernel(const bf16_t* __restrict__ A, const bf16_t* __restrict__ B,
                      float* __restrict__ Cout, const float* __restrict__ bna) {
  __shared__ __align__(16) bf16_t As[128 * 64];
  __shared__ __align__(16) bf16_t Bs[128 * 64];
  const int tid = threadIdx.x, wid = tid >> 6, lane = tid & 63;
  const int fr = lane & 15, fg = lane >> 4;
  const int wm = (wid >> 1) * 64, wn = (wid & 1) * 64;
  const int m0 = blockIdx.y * 128, n0 = blockIdx.x * 128;
  const int srow = tid >> 3;
  const int soff = (((tid & 7) ^ (srow & 7)) * 8);
  const bf16_t* Ab = A + (size_t)m0 * 1024;
  const bf16_t* Bb = B + (size_t)n0 * 1024;

  f32x4 acc[4][4] = {};

  for (int kk = 0; kk < 1024; kk += 64) {
    __syncthreads();
#pragma unroll
    for (int r = 0; r < 4; ++r) {
      gload16(Ab + (size_t)(srow + 32 * r) * 1024 + kk + soff, As + (wid * 8 + 32 * r) * 64);
      gload16(Bb + (size_t)(srow + 32 * r) * 1024 + kk + soff, Bs + (wid * 8 + 32 * r) * 64);
    }
    __syncthreads();
#pragma unroll
    for (int ks = 0; ks < 2; ++ks) {
      bf16x8 af[4], bfr[4];
#pragma unroll
      for (int i = 0; i < 4; ++i)
        af[i]  = *(const bf16x8*)&As[(wm + i * 16 + fr) * 64 + (((ks * 4 + fg) ^ (fr & 7)) * 8)];
#pragma unroll
      for (int j = 0; j < 4; ++j)
        bfr[j] = *(const bf16x8*)&Bs[(wn + j * 16 + fr) * 64 + (((ks * 4 + fg) ^ (fr & 7)) * 8)];
#pragma unroll
      for (int i = 0; i < 4; ++i)
#pragma unroll
        for (int j = 0; j < 4; ++j)
          acc[i][j] = __builtin_amdgcn_mfma_f32_16x16x32_bf16(af[i], bfr[j], acc[i][j], 0, 0, 0);
    }
  }

#pragma unroll
  for (int i = 0; i < 4; ++i)
#pragma unroll
    for (int r = 0; r < 4; ++r) {
      const int m = m0 + wm + i * 16 + fg * 4 + r;
      const float sh = bna[m];
#pragma unroll
      for (int j = 0; j < 4; ++j)
        Cout[(size_t)m * N_PIX + n0 + wn + j * 16 + fr] = acc[i][j][r] + sh;
    }
}

// ---------------- K2: fused dw 5x5 + grouped 1x1; channel-split async pipeline, XCD-remapped ----------------
__global__ __launch_bounds__(256)
void dwpw_kernel(const h16* __restrict__ Qb, const h16* __restrict__ KV,
                 const float* __restrict__ wdw, const float* __restrict__ wpw,
                 const h16* __restrict__ zp, h16* __restrict__ y) {
  const int bidHW = blockIdx.x + (blockIdx.y << 4);          // gridDim = (16,192)
  const int work  = (bidHW & 7) * 384 + (bidHW >> 3);
  const int g = work >> 4, t = work & 15;
  const int typ = g % 3, head = g / 3;
  const int ty0 = (t >> 1) * 16, tx0 = (t & 1) * 64;
  const int tid = threadIdx.x, wid = tid >> 6, lane = tid & 63;
  __shared__ __align__(16) h16 sin_[8][20][80];
  __shared__ h16x2 swd2[8][25];
  __shared__ h16x2 swp2[8][8];
  if (tid < 200) {
    const h16 w = (h16)wdw[(g * 8 + tid / 25) * 25 + tid % 25];
    h16x2 w2; w2[0] = w; w2[1] = w;
    swd2[tid / 25][tid % 25] = w2;
  }
  if (tid < 64) {
    const h16 w = (h16)wpw[(g * 8 + (tid >> 3)) * 8 + (tid & 7)];
    h16x2 w2; w2[0] = w; w2[1] = w;
    swp2[tid >> 3][tid & 7] = w2;
  }
  const h16* plane = (typ == 0) ? (Qb + (size_t)head * 8 * N_PIX)
                                : (KV + (size_t)((typ == 2 ? 512 : 0) + head * 8) * N_PIX);
  h16* sflat = &sin_[0][0][0];

  auto stageChunk = [&](int id) {   // id in [0,1600): [ch][row][c6]
    const int ch  = id / 200;
    const int rem = id - ch * 200;
    const int row = rem / 10;
    const int c6  = rem - row * 10;
    const int gy  = ty0 + row - 2;
    const int gx  = tx0 + c6 * 8 - 8;
    const bool ok = ((unsigned)gy < 128u) && ((unsigned)gx < 128u);
    const h16* src = ok ? (plane + (size_t)ch * N_PIX + gy * 128 + gx) : zp;
    gload16(src, sflat + (size_t)id * 8);
  };

  for (int base = wid * 64; base < 832; base += 256) stageChunk(base + lane);
  __syncthreads();  // drains pass-1 DMA (+ weight stores)
  for (int base = 832 + wid * 64; base < 1600; base += 256) stageChunk(base + lane);

  const int px4 = (tid & 15) * 4, py = tid >> 4;
  h16x2 dwa[8][2];

  auto dwCh = [&](int ch) {
    h16x2 A0 = 0, A1 = 0;
#pragma unroll
    for (int di = 0; di < 5; ++di) {
      const uint2 w0 = *(const uint2*)&sin_[ch][py + di][px4 + 4];
      const uint2 w1 = *(const uint2*)&sin_[ch][py + di][px4 + 8];
      const uint2 w2v = *(const uint2*)&sin_[ch][py + di][px4 + 12];
      const unsigned u1 = w0.y, u2 = w1.x, u3 = w1.y, u4 = w2v.x;
      const h16x2 P2 = __builtin_bit_cast(h16x2, u1);
      const h16x2 P3 = __builtin_bit_cast(h16x2, (u2 << 16) | (u1 >> 16));
      const h16x2 P4 = __builtin_bit_cast(h16x2, u2);
      const h16x2 P5 = __builtin_bit_cast(h16x2, (u3 << 16) | (u2 >> 16));
      const h16x2 P6 = __builtin_bit_cast(h16x2, u3);
      const h16x2 P7 = __builtin_bit_cast(h16x2, (u4 << 16) | (u3 >> 16));
      const h16x2 P8 = __builtin_bit_cast(h16x2, u4);
      h16x2 wd;
      wd = swd2[ch][di * 5 + 0]; A0 += wd * P2; A1 += wd * P4;
      wd = swd2[ch][di * 5 + 1]; A0 += wd * P3; A1 += wd * P5;
      wd = swd2[ch][di * 5 + 2]; A0 += wd * P4; A1 += wd * P6;
      wd = swd2[ch][di * 5 + 3]; A0 += wd * P5; A1 += wd * P7;
      wd = swd2[ch][di * 5 + 4]; A0 += wd * P6; A1 += wd * P8;
    }
    dwa[ch][0] = A0; dwa[ch][1] = A1;
  };

#pragma unroll
  for (int ch = 0; ch < 4; ++ch) dwCh(ch);   // overlaps pass-2 DMA
  __syncthreads();  // drains pass-2 DMA
#pragma unroll
  for (int ch = 4; ch < 8; ++ch) dwCh(ch);

#pragma unroll
  for (int oc = 0; oc < 8; ++oc) {
    h16x2 o0 = 0, o1 = 0;
#pragma unroll
    for (int ic = 0; ic < 8; ++ic) {
      const h16x2 w = swp2[oc][ic];
      o0 += w * dwa[ic][0];
      o1 += w * dwa[ic][1];
    }
    h16x4 ov; ov[0] = o0[0]; ov[1] = o0[1]; ov[2] = o1[0]; ov[3] = o1[1];
    *(h16x4*)&y[(size_t)(8 * g + oc) * N_PIX + (ty0 + py) * 128 + tx0 + px4] = ov;
  }
}

// ---------------- K3a: per-slice partial vk[d][e] = sum_n v_d * relu(k_e) (+ k-sum row) ----------------
__global__ __launch_bounds__(256)
void vk_partial_kernel(const h16* __restrict__ KV, const h16* __restrict__ yb,
                       float* __restrict__ part) {
  const int h = blockIdx.y, s = blockIdx.x;
  const h16 *kb, *vb;
  if (h < 64) {
    kb = KV + (size_t)(h * 8) * N_PIX;
    vb = KV + (size_t)(512 + h * 8) * N_PIX;
  } else {
    kb = yb + (size_t)(24 * (h - 64) + 8) * N_PIX;
    vb = yb + (size_t)(24 * (h - 64) + 16) * N_PIX;
  }
  float a[8][8] = {};
  float ak[8] = {};
  const int p0 = s * 2048 + (int)threadIdx.x * 8;
  float kq[8][8], vq[8][8];
#pragma unroll
  for (int e = 0; e < 8; ++e) {
    h16x8 kk = *(const h16x8*)&kb[(size_t)e * N_PIX + p0];
#pragma unroll
    for (int u = 0; u < 8; ++u) kq[e][u] = fmaxf(0.f, (float)kk[u]);
  }
#pragma unroll
  for (int d = 0; d < 8; ++d) {
    h16x8 vv = *(const h16x8*)&vb[(size_t)d * N_PIX + p0];
#pragma unroll
    for (int u = 0; u < 8; ++u) vq[d][u] = (float)vv[u];
  }
#pragma unroll
  for (int d = 0; d < 8; ++d)
#pragma unroll
    for (int e = 0; e < 8; ++e)
#pragma unroll
      for (int u = 0; u < 8; ++u) a[d][e] += vq[d][u] * kq[e][u];
#pragma unroll
  for (int e = 0; e < 8; ++e)
#pragma unroll
    for (int u = 0; u < 8; ++u) ak[e] += kq[e][u];

  __shared__ float red[4][72];
  const int lane = threadIdx.x & 63, wid = threadIdx.x >> 6;
#pragma unroll
  for (int i = 0; i < 72; ++i) {
    float v = (i < 64) ? a[i >> 3][i & 7] : ak[i - 64];
    v += __shfl_xor(v, 32); v += __shfl_xor(v, 16); v += __shfl_xor(v, 8);
    v += __shfl_xor(v, 4);  v += __shfl_xor(v, 2);  v += __shfl_xor(v, 1);
    if (lane == 0) red[wid][i] = v;
  }
  __syncthreads();
  if (threadIdx.x < 72) {
    const float sum_ = red[0][threadIdx.x] + red[1][threadIdx.x] + red[2][threadIdx.x] + red[3][threadIdx.x];
    part[((size_t)h * 8 + s) * 72 + threadIdx.x] = sum_;
  }
}

// ---------------- K3b: deterministic reduce of 8 slices ----------------
__global__ __launch_bounds__(128)
void vk_reduce_kernel(const float* __restrict__ part, float* __restrict__ vk) {
  const int h = blockIdx.x;
  const int i = threadIdx.x;
  if (i < 72) {
    float s = 0.f;
#pragma unroll
    for (int t = 0; t < 8; ++t) s += part[((size_t)h * 8 + t) * 72 + i];
    vk[(size_t)h * 72 + i] = s;
  }
}

// ---------------- K3c: W2[m][h*8+e] = sum_d wpb[m][h*8+d] * vk[h][d][e] ----------------
__global__ __launch_bounds__(256)
void w2_kernel(const bf16_t* __restrict__ wpb, const float* __restrict__ vkm,
               bf16_t* __restrict__ W2) {
  const int idx = blockIdx.x * 256 + threadIdx.x;
  const int m = idx >> 10, c = idx & 1023;
  const int h = c >> 3, e = c & 7;
  float s = 0.f;
#pragma unroll
  for (int d = 0; d < 8; ++d)
    s += (float)wpb[(size_t)m * 1024 + h * 8 + d] * vkm[h * 72 + d * 8 + e];
  W2[idx] = (bf16_t)s;
}

// ---------------- K4: qn = relu(q) / den -> qnT bf16 [N][1024]; ak table hoisted, 5 barriers total ----------------
__global__ __launch_bounds__(256)
void qn_kernel(const h16* __restrict__ Qb, const h16* __restrict__ yb,
               const float* __restrict__ vk, bf16_t* __restrict__ qnT) {
  const int n0 = blockIdx.x * 32;
  const int tid = threadIdx.x;
  const int px = tid & 31, hl = tid >> 5;
  __shared__ __align__(16) bf16_t att_s[32 * 512];
  __shared__ float ak_all[128][8];   // 4 KB: denominators for all 128 heads
#pragma unroll
  for (int r = 0; r < 4; ++r) {
    const int i = tid + r * 256;  // 1024 entries
    ak_all[i >> 3][i & 7] = vk[(size_t)(i >> 3) * 72 + 64 + (i & 7)];
  }
  __syncthreads();
  for (int grp = 0; grp < 2; ++grp) {
    for (int hg = 0; hg < 8; ++hg) {   // no barriers: disjoint att_s writes per (px,chunk)
      const int hh = hg * 8 + hl;      // head within half (0..63)
      const int habs = grp * 64 + hh;
      float q[8];
      if (grp == 0) {
        const h16* plane = Qb + (size_t)(hh * 8) * N_PIX + n0 + px;
#pragma unroll
        for (int e = 0; e < 8; ++e) q[e] = fmaxf(0.f, (float)plane[(size_t)e * N_PIX]);
      } else {
        const h16* plane = yb + (size_t)(24 * hh) * N_PIX + n0 + px;
#pragma unroll
        for (int e = 0; e < 8; ++e) q[e] = fmaxf(0.f, (float)plane[(size_t)e * N_PIX]);
      }
      float den = 1e-15f;
#pragma unroll
      for (int e = 0; e < 8; ++e) den += ak_all[habs][e] * q[e];
      const float rden = 1.0f / den;
      bf16x8 r8;
#pragma unroll
      for (int e = 0; e < 8; ++e) r8[e] = (bf16_t)(q[e] * rden);
      const int chunk = hg * 8 + hl;
      *(bf16x8*)&att_s[px * 512 + ((chunk ^ (px & 7)) << 3)] = r8;
    }
    __syncthreads();   // att_s filled
    bf16_t* dst = qnT + (size_t)n0 * 1024 + grp * 512;
    for (int i = tid; i < 2048; i += 256) {
      const int r = i >> 6, cc = i & 63;
      bf16x8 v = *(const bf16x8*)&att_s[r * 512 + (((cc ^ (r & 7))) << 3)];
      *(bf16x8*)&dst[(size_t)r * 1024 + cc * 8] = v;
    }
    __syncthreads();   // write-out done before att_s refilled
  }
}

// ---------------- launch ----------------
extern "C" void kernel_launch(void* const* d_in, const int* in_sizes, int n_in,
                              void* d_out, int out_size, void* d_ws, size_t ws_size,
                              hipStream_t stream) {
  if (ws_size < WS_NEEDED) return;
  const float* x      = (const float*)d_in[0];
  const float* w_qkv  = (const float*)d_in[1];
  const float* w_dw   = (const float*)d_in[2];
  const float* w_pw   = (const float*)d_in[3];
  const float* w_proj = (const float*)d_in[4];
  const float* gam    = (const float*)d_in[5];
  const float* bet    = (const float*)d_in[6];
  const float* mu     = (const float*)d_in[7];
  const float* va     = (const float*)d_in[8];

  char* w = (char*)d_ws;
  h16*    Qb   = (h16*)(w + OFF_QB);
  h16*    KV   = (h16*)(w + OFF_KV);
  h16*    yb   = (h16*)(w + OFF_Y);
  h16*    xT   = (h16*)(w + OFF_XT);    // aliased with qnT (dead after fix)
  h16*    xTl  = (h16*)(w + OFF_XTL);
  bf16_t* qnT  = (bf16_t*)(w + OFF_ATT);
  h16*    wall = (h16*)(w + OFF_WALL);
  bf16_t* wpb  = (bf16_t*)(w + OFF_WP);
  bf16_t* W2   = (bf16_t*)(w + OFF_W2);
  float*  vk   = (float*)(w + OFF_VK);
  float*  part = (float*)(w + OFF_VKP);
  float*  bna  = (float*)(w + OFF_BNA);
  float*  zp   = (float*)(w + OFF_ZP);

  dim3 blk(256);
  prep_kernel<<<dim3((PREP_TOT + 255) / 256), blk, 0, stream>>>(
      w_qkv, w_proj, gam, bet, mu, va, wall, wpb, bna, zp);

  for (int b = 0; b < 2; ++b) {
    const float* xb = x + (size_t)b * 512 * N_PIX;
    float* outb = (float*)d_out + (size_t)b * 512 * N_PIX;
    // K0a: x -> xT (f16) + xT_lo (residual f16)
    xpose_kernel<<<dim3(512, 16), blk, 0, stream>>>(xb, xT, xTl);
    // K1: unified qkv GEMM (f16 MFMA, K=512, 128x128 tile, 2-phase dbuf) -> Qb/KV
    gemm_qkv_kernel<<<dim3(128, 12), blk, 0, stream>>>(wall, xT, Qb, KV);
    // K1b: knife-edge detect + wave-parallel exact in-place repair of Qb
    fix_kernel<<<dim3(64, 64), blk, 0, stream>>>(w_qkv, xT, xTl, Qb);
    // K2: fused dw 5x5 + grouped pw -> y f16 (channel-split pipeline, XCD remap)
    dwpw_kernel<<<dim3(16, 192), blk, 0, stream>>>(Qb, KV, w_dw, w_pw, (const h16*)zp, yb);
    // K3: vk accumulation + W2 fold
    vk_partial_kernel<<<dim3(8, 128), blk, 0, stream>>>(KV, yb, part);
    vk_reduce_kernel<<<dim3(128), dim3(128), 0, stream>>>(part, vk);
    w2_kernel<<<dim3(512 * 1024 / 256), blk, 0, stream>>>(wpb, vk, W2);
    // K4: qn = relu(Qb)/den -> qnT
    qn_kernel<<<dim3(512), blk, 0, stream>>>(Qb, yb, vk, qnT);
    // K5: out = W2 x qnT + bna (128x128 tile)
    gemm_proj_kernel<<<dim3(128, 4), blk, 0, stream>>>(W2, qnT, outb, bna);
  }
}